// Round 3
// baseline (99.763 us; speedup 1.0000x reference)
//
#include <hip/hip_runtime.h>
#include <hip/hip_cooperative_groups.h>

namespace cg = cooperative_groups;

// CLUB loss, algebraically collapsed to O(N*d) streaming reductions:
//   loss = -0.5/N * S_pos + 0.5/N^2 * ( dot(S_invv, S_x2) - 2*dot(S_muinvv, S_x) + N*S_c )
// Single cooperative kernel: phase1 per-block partial slots -> grid sync ->
// phase2 column-parallel slot reduce -> grid sync -> phase3 scalar.
//
// ws doubles layout: [0, 256*258) per-block slots | [SOFF, SOFF+258) global sums

#define NROWS 16384
#define DDIM  64
#define GRID  256
#define SLOTW 258                // 4*64 vector partials + {S_c, S_pos}
#define SOFF  (GRID * SLOTW)

__global__ __launch_bounds__(256) void club_coop(const float* __restrict__ x,
                                                 const float* __restrict__ mu,
                                                 const float* __restrict__ logvar,
                                                 double* __restrict__ ws,
                                                 float* __restrict__ out) {
    __shared__ float  xt[64 * 65];   // padded transpose tile (2-way bank access = free)
    __shared__ double red[256];

    const int tid = threadIdx.x;
    const int bid = blockIdx.x;

    // ---------------- phase 1: per-block partials over one 64-row tile ----------------
    const int i0  = bid * 64;
    const int b   = i0 >> 10;        // h*w = 1024 rows per batch image
    const int hw0 = i0 & 1023;
    const float* xb = x + (size_t)b * 65536 + hw0;

    #pragma unroll
    for (int t = tid; t < 4096; t += 256) {
        const int dd = t >> 6, j = t & 63;
        xt[dd * 65 + j] = xb[(size_t)dd * 1024 + j];     // coalesced 64-float rows
    }
    __syncthreads();

    const int d  = tid & 63;         // lane -> column d (coalesced mu/logvar)
    const int j0 = (tid >> 6) * 16;  // wave -> row sub-block

    double a_x = 0.0, a_x2 = 0.0, a_iv = 0.0, a_miv = 0.0, a_c = 0.0, a_pos = 0.0;
    #pragma unroll
    for (int k = 0; k < 16; ++k) {
        const int j  = j0 + k;                  // wave-uniform row
        const float xv = xt[d * 65 + j];
        const int idx  = (i0 + j) * DDIM + d;   // coalesced
        const float m  = mu[idx];
        const float lv = logvar[idx];
        const float iv = expf(-lv);
        const float t2 = xv - m;
        a_x   += (double)xv;
        a_x2  += (double)(xv * xv);
        a_iv  += (double)iv;
        a_miv += (double)(m * iv);
        a_c   += (double)(m * m * iv);
        a_pos += (double)(t2 * t2 * iv);
    }

    double* slot = ws + (size_t)bid * SLOTW;

    #define VR(val, base)                                                              \
        red[tid] = (val); __syncthreads();                                             \
        if (tid < 64) slot[(base) + tid] =                                             \
            red[tid] + red[tid + 64] + red[tid + 128] + red[tid + 192];                \
        __syncthreads();
    VR(a_x,   0)
    VR(a_x2,  64)
    VR(a_iv,  128)
    VR(a_miv, 192)
    #undef VR

    red[tid] = a_c; __syncthreads();
    if (tid < 64) {
        double s = red[tid] + red[tid + 64] + red[tid + 128] + red[tid + 192];
        #pragma unroll
        for (int off = 32; off > 0; off >>= 1) s += __shfl_down(s, off, 64);
        if (tid == 0) slot[256] = s;
    }
    __syncthreads();
    red[tid] = a_pos; __syncthreads();
    if (tid < 64) {
        double s = red[tid] + red[tid + 64] + red[tid + 128] + red[tid + 192];
        #pragma unroll
        for (int off = 32; off > 0; off >>= 1) s += __shfl_down(s, off, 64);
        if (tid == 0) slot[257] = s;
    }

    __threadfence();                 // device-scope release (cross-XCD)
    cg::this_grid().sync();

    // ---------------- phase 2: column-parallel slot reduction ----------------
    // Block c reduces column c across the 256 slots (blocks 0,1 also take 256,257).
    for (int c = bid; c < SLOTW; c += GRID) {
        red[tid] = ws[(size_t)tid * SLOTW + c];
        __syncthreads();
        if (tid < 128) red[tid] += red[tid + 128];
        __syncthreads();
        if (tid < 64) {
            double s = red[tid] + red[tid + 64];
            #pragma unroll
            for (int off = 32; off > 0; off >>= 1) s += __shfl_down(s, off, 64);
            if (tid == 0) ws[SOFF + c] = s;
        }
        __syncthreads();
    }

    __threadfence();
    cg::this_grid().sync();

    // ---------------- phase 3: final dot + scalar ----------------
    if (bid == 0 && tid < 64) {
        const double* S = ws + SOFF;
        double term = S[128 + tid] * S[64 + tid] - 2.0 * S[192 + tid] * S[tid];
        #pragma unroll
        for (int off = 32; off > 0; off >>= 1) term += __shfl_down(term, off, 64);
        if (tid == 0) {
            const double Nd   = (double)NROWS;
            const double sumD = term + Nd * S[256];
            out[0] = (float)(-0.5 / Nd * S[257] + 0.5 / (Nd * Nd) * sumD);
        }
    }
}

extern "C" void kernel_launch(void* const* d_in, const int* in_sizes, int n_in,
                              void* d_out, int out_size, void* d_ws, size_t ws_size,
                              hipStream_t stream) {
    const float* x      = (const float*)d_in[0];
    const float* mu     = (const float*)d_in[1];
    const float* logvar = (const float*)d_in[2];
    float*  out = (float*)d_out;
    double* ws  = (double*)d_ws;
    // needs (256*258 + 258) * 8 B = ~530 KB of workspace (ws is ~268 MB)

    void* args[] = {(void*)&x, (void*)&mu, (void*)&logvar, (void*)&ws, (void*)&out};
    hipLaunchCooperativeKernel((void*)club_coop, dim3(GRID), dim3(256), args, 0, stream);
}

// Round 4
// 52.471 us; speedup vs baseline: 1.9013x; 1.9013x over previous
//
#include <hip/hip_runtime.h>

// CLUB loss, algebraically collapsed to O(N*d) streaming reductions:
//   loss = -0.5/N * S_pos + 0.5/N^2 * ( dot(S_invv,S_x2) - 2*dot(S_muinvv,S_x) + N*S_c )
// Single kernel, last-block-done pattern (no grid.sync, no memset):
//   128 blocks -> transposed partial slots ws[c*128 + b] -> device-scope counter ->
//   last block gathers columns (coalesced) + final dot + scalar.

#define NROWS 16384
#define DDIM  64
#define GRID  128           // blocks; each handles 2 tiles of 64 rows
#define TILES 256
#define NCOL  258           // 4*64 vector partials + {S_c, S_pos}

__device__ int g_club_counter = 0;   // zero at module load; last block re-zeros each run

__global__ __launch_bounds__(256) void club_fused(const float* __restrict__ x,
                                                  const float* __restrict__ mu,
                                                  const float* __restrict__ logvar,
                                                  double* __restrict__ ws,
                                                  float* __restrict__ out) {
    __shared__ float  xt[64 * 65];   // padded transpose tile (2-way bank access = free)
    __shared__ double red[256];
    __shared__ double S[NCOL];
    __shared__ int    is_last;

    const int tid = threadIdx.x;
    const int bid = blockIdx.x;
    const int d   = tid & 63;        // lane -> column d (coalesced mu/logvar)
    const int j0  = (tid >> 6) * 16; // wave -> row sub-block

    double a_x = 0.0, a_x2 = 0.0, a_iv = 0.0, a_miv = 0.0, a_c = 0.0, a_pos = 0.0;

    // ---------------- phase 1: partials over this block's tiles ----------------
    for (int tile = bid; tile < TILES; tile += GRID) {
        const int i0  = tile * 64;
        const int b   = i0 >> 10;        // h*w = 1024 rows per batch image
        const int hw0 = i0 & 1023;       // multiple of 64 -> 256B-aligned
        const float* xb = x + (size_t)b * 65536 + hw0;

        __syncthreads();                 // protect xt from prior-iter readers
        #pragma unroll
        for (int t = tid; t < 1024; t += 256) {      // float4-staged x tile
            const int dd = t >> 4, j4 = (t & 15) * 4;
            const float4 v = *(const float4*)(xb + (size_t)dd * 1024 + j4);
            float* p = &xt[dd * 65 + j4];
            p[0] = v.x; p[1] = v.y; p[2] = v.z; p[3] = v.w;
        }
        __syncthreads();

        #pragma unroll
        for (int k = 0; k < 16; ++k) {
            const int j  = j0 + k;                   // wave-uniform row
            const float xv = xt[d * 65 + j];
            const int idx  = (i0 + j) * DDIM + d;    // coalesced
            const float m  = mu[idx];
            const float lv = logvar[idx];
            const float iv = expf(-lv);
            const float t2 = xv - m;
            a_x   += (double)xv;
            a_x2  += (double)(xv * xv);
            a_iv  += (double)iv;
            a_miv += (double)(m * iv);
            a_c   += (double)(m * m * iv);
            a_pos += (double)(t2 * t2 * iv);
        }
    }

    // Block-level reduce (4 threads per d), write TRANSPOSED slots ws[c*GRID + bid].
    #define VR(val, base)                                                              \
        red[tid] = (val); __syncthreads();                                             \
        if (tid < 64) ws[(size_t)((base) + tid) * GRID + bid] =                        \
            red[tid] + red[tid + 64] + red[tid + 128] + red[tid + 192];                \
        __syncthreads();
    VR(a_x,   0)
    VR(a_x2,  64)
    VR(a_iv,  128)
    VR(a_miv, 192)
    #undef VR

    red[tid] = a_c; __syncthreads();
    if (tid < 64) {
        double s = red[tid] + red[tid + 64] + red[tid + 128] + red[tid + 192];
        #pragma unroll
        for (int off = 32; off > 0; off >>= 1) s += __shfl_down(s, off, 64);
        if (tid == 0) ws[(size_t)256 * GRID + bid] = s;
    }
    __syncthreads();
    red[tid] = a_pos; __syncthreads();
    if (tid < 64) {
        double s = red[tid] + red[tid + 64] + red[tid + 128] + red[tid + 192];
        #pragma unroll
        for (int off = 32; off > 0; off >>= 1) s += __shfl_down(s, off, 64);
        if (tid == 0) ws[(size_t)257 * GRID + bid] = s;
    }

    // ---------------- last-block election (device-scope) ----------------
    __threadfence();                 // release: slot stores visible device-wide
    __syncthreads();
    if (tid == 0) {
        const int old = atomicAdd(&g_club_counter, 1);
        is_last = (old == GRID - 1);
        if (is_last) g_club_counter = 0;   // self-reset for the next (replayed) launch
    }
    __syncthreads();
    if (!is_last) return;
    __threadfence();                 // acquire: see all blocks' slot stores

    // ---------------- last block: coalesced column gather ----------------
    const int wave = tid >> 6;
    const int lane = tid & 63;
    for (int c = wave; c < NCOL; c += 4) {
        const double* col = ws + (size_t)c * GRID;
        double s = col[lane] + col[lane + 64];       // 2 coalesced 512B loads
        #pragma unroll
        for (int off = 32; off > 0; off >>= 1) s += __shfl_down(s, off, 64);
        if (lane == 0) S[c] = s;
    }
    __syncthreads();

    // ---------------- final dot + scalar ----------------
    if (tid < 64) {
        double term = S[128 + tid] * S[64 + tid] - 2.0 * S[192 + tid] * S[tid];
        #pragma unroll
        for (int off = 32; off > 0; off >>= 1) term += __shfl_down(term, off, 64);
        if (tid == 0) {
            const double Nd   = (double)NROWS;
            const double sumD = term + Nd * S[256];
            out[0] = (float)(-0.5 / Nd * S[257] + 0.5 / (Nd * Nd) * sumD);
        }
    }
}

extern "C" void kernel_launch(void* const* d_in, const int* in_sizes, int n_in,
                              void* d_out, int out_size, void* d_ws, size_t ws_size,
                              hipStream_t stream) {
    const float* x      = (const float*)d_in[0];
    const float* mu     = (const float*)d_in[1];
    const float* logvar = (const float*)d_in[2];
    float*  out = (float*)d_out;
    double* ws  = (double*)d_ws;   // needs 258*128*8 B = 264 KB

    club_fused<<<GRID, 256, 0, stream>>>(x, mu, logvar, ws, out);
}

// Round 5
// 27.055 us; speedup vs baseline: 3.6875x; 1.9394x over previous
//
#include <hip/hip_runtime.h>

// CLUB loss, algebraically collapsed to O(N*d) streaming reductions:
//   loss = -0.5/N * S_pos + 0.5/N^2 * ( dot(S_invv,S_x2) - 2*dot(S_muinvv,S_x) + N*S_c )
// Single kernel, last-block-done, O(1) tail:
//   256 blocks -> block-reduced partials -> replicated f64 atomicAdd into
//   __device__ accumulator (contention 64/address) -> last block reads 8 KB,
//   does the 64-dot, writes the scalar, and re-zeros the accumulator for the
//   next replay (dispatch-end L2 writeback makes the reset visible).

#define NROWS 16384
#define DDIM  64
#define GRID  256           // one 64-row tile per block
#define NCOL  258           // 4*64 vector partials + {S_c, S_pos}
#define NREP  4             // accumulator replicas (contention / 4)

__device__ double g_acc[NREP * NCOL];   // zero at module load; self-reset each run
__device__ int    g_counter = 0;

__global__ __launch_bounds__(256) void club_fused(const float* __restrict__ x,
                                                  const float* __restrict__ mu,
                                                  const float* __restrict__ logvar,
                                                  float* __restrict__ out) {
    __shared__ double red[256];
    __shared__ double S[NCOL];
    __shared__ int    is_last;

    const int tid = threadIdx.x;
    const int bid = blockIdx.x;
    const int d   = tid & 63;        // lane -> column d
    const int g   = tid >> 6;        // wave -> 16-row group
    const int i0  = bid * 64;
    const int b   = i0 >> 10;        // h*w = 1024 rows per batch image
    const int hw0 = i0 & 1023;       // multiple of 64

    // ---- phase 1: direct reads, no LDS staging ----
    // x[b][d][hw0+g*16 .. +15]: 4 x float4 per thread, 64B-aligned; the 4 loads
    // consume whole 64B lines (L1 catches the 3 reuses per line).
    const float* xp = x + (size_t)b * 65536 + (size_t)d * 1024 + hw0 + g * 16;
    float xr[16];
    *(float4*)(&xr[0])  = ((const float4*)xp)[0];
    *(float4*)(&xr[4])  = ((const float4*)xp)[1];
    *(float4*)(&xr[8])  = ((const float4*)xp)[2];
    *(float4*)(&xr[12]) = ((const float4*)xp)[3];

    double a_x = 0.0, a_x2 = 0.0, a_iv = 0.0, a_miv = 0.0, a_c = 0.0, a_pos = 0.0;
    const int base_idx = (i0 + g * 16) * DDIM + d;   // coalesced mu/logvar
    #pragma unroll
    for (int k = 0; k < 16; ++k) {
        const float xv = xr[k];
        const float m  = mu[base_idx + k * DDIM];
        const float lv = logvar[base_idx + k * DDIM];
        const float iv = expf(-lv);
        const float t2 = xv - m;
        a_x   += (double)xv;
        a_x2  += (double)(xv * xv);
        a_iv  += (double)iv;
        a_miv += (double)(m * iv);
        a_c   += (double)(m * m * iv);
        a_pos += (double)(t2 * t2 * iv);
    }

    // ---- block reduce (4 threads per d) + replicated atomic fan-in ----
    double* acc = g_acc + (size_t)(bid & (NREP - 1)) * NCOL;

    #define VR(val, base)                                                              \
        red[tid] = (val); __syncthreads();                                             \
        if (tid < 64) atomicAdd(&acc[(base) + tid],                                    \
            red[tid] + red[tid + 64] + red[tid + 128] + red[tid + 192]);               \
        __syncthreads();
    VR(a_x,   0)
    VR(a_x2,  64)
    VR(a_iv,  128)
    VR(a_miv, 192)
    #undef VR

    red[tid] = a_c; __syncthreads();
    if (tid < 64) {
        double s = red[tid] + red[tid + 64] + red[tid + 128] + red[tid + 192];
        #pragma unroll
        for (int off = 32; off > 0; off >>= 1) s += __shfl_down(s, off, 64);
        if (tid == 0) atomicAdd(&acc[256], s);
    }
    __syncthreads();
    red[tid] = a_pos; __syncthreads();
    if (tid < 64) {
        double s = red[tid] + red[tid + 64] + red[tid + 128] + red[tid + 192];
        #pragma unroll
        for (int off = 32; off > 0; off >>= 1) s += __shfl_down(s, off, 64);
        if (tid == 0) atomicAdd(&acc[257], s);
    }

    // ---- last-block election ----
    __threadfence();                       // release
    __syncthreads();
    if (tid == 0) {
        const int old = atomicAdd(&g_counter, 1);
        is_last = (old == GRID - 1);
        if (is_last) atomicExch(&g_counter, 0);   // reset for next replay
    }
    __syncthreads();
    if (!is_last) return;
    __threadfence();                       // acquire: invalidate stale L2

    // ---- O(1) tail: 8 KB gather, reset, final dot ----
    for (int c = tid; c < NCOL; c += 256) {
        double s = 0.0;
        #pragma unroll
        for (int r = 0; r < NREP; ++r) {
            s += g_acc[r * NCOL + c];
            g_acc[r * NCOL + c] = 0.0;     // visible next launch via dispatch-end writeback
        }
        S[c] = s;
    }
    __syncthreads();

    if (tid < 64) {
        double term = S[128 + tid] * S[64 + tid] - 2.0 * S[192 + tid] * S[tid];
        #pragma unroll
        for (int off = 32; off > 0; off >>= 1) term += __shfl_down(term, off, 64);
        if (tid == 0) {
            const double Nd   = (double)NROWS;
            const double sumD = term + Nd * S[256];
            out[0] = (float)(-0.5 / Nd * S[257] + 0.5 / (Nd * Nd) * sumD);
        }
    }
}

extern "C" void kernel_launch(void* const* d_in, const int* in_sizes, int n_in,
                              void* d_out, int out_size, void* d_ws, size_t ws_size,
                              hipStream_t stream) {
    const float* x      = (const float*)d_in[0];
    const float* mu     = (const float*)d_in[1];
    const float* logvar = (const float*)d_in[2];
    float* out = (float*)d_out;

    club_fused<<<GRID, 256, 0, stream>>>(x, mu, logvar, out);
}

// Round 6
// 17.606 us; speedup vs baseline: 5.6665x; 1.5367x over previous
//
#include <hip/hip_runtime.h>

// CLUB loss, algebraically collapsed to O(N*d) streaming reductions:
//   loss = -0.5/N * S_pos + 0.5/N^2 * ( dot(S_invv,S_x2) - 2*dot(S_muinvv,S_x) + N*S_c )
// Single kernel, last-block-done, fence-free:
//   - all cross-block traffic is device-scope atomics (coherent at fabric; no
//     __threadfence L2 writeback/invalidate needed)
//   - release: s_waitcnt vmcnt(0) + barrier before counter bump
//   - acquire: agent-scope atomic loads in the tail (bypass stale L1/L2)
//   - g_acc self-resets via agent-scope atomic stores each run

#define NROWS 16384
#define DDIM  64
#define GRID  256           // one 64-row tile per block
#define NCOL  258           // 4*64 vector partials + {S_c, S_pos}
#define NREP  4             // accumulator replicas (64-way contention each)

__device__ double g_acc[NREP * NCOL];   // zero at module load; self-reset each run
__device__ int    g_counter = 0;

__global__ __launch_bounds__(256) void club_fused(const float* __restrict__ x,
                                                  const float* __restrict__ mu,
                                                  const float* __restrict__ logvar,
                                                  float* __restrict__ out) {
    __shared__ float  xt[64 * 65];   // padded x tile: 2-way bank access everywhere (free)
    __shared__ double red[256];
    __shared__ double S[NCOL];
    __shared__ int    is_last;

    const int tid = threadIdx.x;
    const int bid = blockIdx.x;
    const int i0  = bid * 64;
    const int b   = i0 >> 10;        // h*w = 1024 rows per batch image
    const int hw0 = i0 & 1023;       // multiple of 64

    // ---- phase 1a: stage x[b, :, hw0:hw0+64] into LDS (coalesced float4) ----
    const float* xb = x + (size_t)b * 65536 + hw0;
    #pragma unroll
    for (int t = tid; t < 1024; t += 256) {
        const int dd = t >> 4, j4 = (t & 15) * 4;
        const float4 v = *(const float4*)(xb + (size_t)dd * 1024 + j4);
        float* p = &xt[dd * 65 + j4];
        p[0] = v.x; p[1] = v.y; p[2] = v.z; p[3] = v.w;
    }
    __syncthreads();

    // ---- phase 1b: per-thread partials (lane=d -> coalesced mu/logvar) ----
    const int d  = tid & 63;
    const int j0 = (tid >> 6) * 16;
    double a_x = 0.0, a_x2 = 0.0, a_iv = 0.0, a_miv = 0.0, a_c = 0.0, a_pos = 0.0;
    const int base_idx = (i0 + j0) * DDIM + d;
    #pragma unroll
    for (int k = 0; k < 16; ++k) {
        const float xv = xt[d * 65 + j0 + k];
        const float m  = mu[base_idx + k * DDIM];
        const float lv = logvar[base_idx + k * DDIM];
        const float iv = expf(-lv);
        const float t2 = xv - m;
        a_x   += (double)xv;
        a_x2  += (double)(xv * xv);
        a_iv  += (double)iv;
        a_miv += (double)(m * iv);
        a_c   += (double)(m * m * iv);
        a_pos += (double)(t2 * t2 * iv);
    }

    // ---- block reduce (4 threads per d) + replicated atomic fan-in ----
    double* acc = g_acc + (size_t)(bid & (NREP - 1)) * NCOL;

    #define VR(val, base)                                                              \
        red[tid] = (val); __syncthreads();                                             \
        if (tid < 64) atomicAdd(&acc[(base) + tid],                                    \
            red[tid] + red[tid + 64] + red[tid + 128] + red[tid + 192]);               \
        __syncthreads();
    VR(a_x,   0)
    VR(a_x2,  64)
    VR(a_iv,  128)
    VR(a_miv, 192)
    #undef VR

    red[tid] = a_c; __syncthreads();
    if (tid < 64) {
        double s = red[tid] + red[tid + 64] + red[tid + 128] + red[tid + 192];
        #pragma unroll
        for (int off = 32; off > 0; off >>= 1) s += __shfl_down(s, off, 64);
        if (tid == 0) atomicAdd(&acc[256], s);
    }
    __syncthreads();
    red[tid] = a_pos; __syncthreads();
    if (tid < 64) {
        double s = red[tid] + red[tid + 64] + red[tid + 128] + red[tid + 192];
        #pragma unroll
        for (int off = 32; off > 0; off >>= 1) s += __shfl_down(s, off, 64);
        if (tid == 0) atomicAdd(&acc[257], s);
    }

    // ---- last-block election (fence-free release) ----
    // Atomics are agent-coherent; just drain them before bumping the counter.
    asm volatile("s_waitcnt vmcnt(0)" ::: "memory");
    __syncthreads();
    if (tid == 0) {
        is_last = (atomicAdd(&g_counter, 1) == GRID - 1);
        if (is_last) atomicExch(&g_counter, 0);   // reset for next replay
    }
    __syncthreads();
    if (!is_last) return;

    // ---- O(1) tail: 8 KB coherent gather + reset (agent-scope, no cache inv) ----
    for (int c = tid; c < NCOL; c += 256) {
        double s = 0.0;
        #pragma unroll
        for (int r = 0; r < NREP; ++r) {
            s += __hip_atomic_load(&g_acc[r * NCOL + c],
                                   __ATOMIC_RELAXED, __HIP_MEMORY_SCOPE_AGENT);
            __hip_atomic_store(&g_acc[r * NCOL + c], 0.0,
                               __ATOMIC_RELAXED, __HIP_MEMORY_SCOPE_AGENT);
        }
        S[c] = s;
    }
    __syncthreads();

    // ---- final dot + scalar ----
    if (tid < 64) {
        double term = S[128 + tid] * S[64 + tid] - 2.0 * S[192 + tid] * S[tid];
        #pragma unroll
        for (int off = 32; off > 0; off >>= 1) term += __shfl_down(term, off, 64);
        if (tid == 0) {
            const double Nd   = (double)NROWS;
            const double sumD = term + Nd * S[256];
            out[0] = (float)(-0.5 / Nd * S[257] + 0.5 / (Nd * Nd) * sumD);
        }
    }
}

extern "C" void kernel_launch(void* const* d_in, const int* in_sizes, int n_in,
                              void* d_out, int out_size, void* d_ws, size_t ws_size,
                              hipStream_t stream) {
    const float* x      = (const float*)d_in[0];
    const float* mu     = (const float*)d_in[1];
    const float* logvar = (const float*)d_in[2];
    float* out = (float*)d_out;

    club_fused<<<GRID, 256, 0, stream>>>(x, mu, logvar, out);
}